// Round 6
// baseline (198.443 us; speedup 1.0000x reference)
//
#include <hip/hip_runtime.h>
#include <math.h>

// BigBird block-sparse attention, bf16 MFMA, double-buffered LDS (1 barrier/tile),
// LDS = exactly 32 KB -> 5 blocks/CU; tile list in registers; exp2-domain softmax.
// B=2 H=16 M=N=4096 D=64 WM=WN=64 R=3 nb=64.
constexpr int B_  = 2;
constexpr int H_  = 16;
constexpr int M_  = 4096;
constexpr int NB_ = 64;
constexpr int R_  = 3;
constexpr float LOG2E  = 1.44269504089f;
constexpr float SCALE2 = 0.125f * LOG2E;          // (1/sqrt(64)) * log2(e)
constexpr float NEG2   = -10000.0f * LOG2E;

constexpr int PER_BH = 62 + 16;             // 62 middle + 2 edges * 8 chunks
constexpr int PACC_OFF = 0;                                  // [BH][2][8][64][64]
constexpr int PM_OFF   = B_ * H_ * 2 * 8 * 64 * 64;          // [BH][2][8][64]
constexpr int PL_OFF   = PM_OFF + B_ * H_ * 2 * 8 * 64;

typedef short bf16x8 __attribute__((ext_vector_type(8)));   // 8 bf16 in 4 VGPRs
typedef float f32x4  __attribute__((ext_vector_type(4)));

__device__ __forceinline__ short bf16s(float x) {
    return __builtin_bit_cast(short, (__bf16)x);
}
__device__ __forceinline__ unsigned pack_bf16(float a, float b) {
    unsigned short ul = __builtin_bit_cast(unsigned short, (__bf16)a);
    unsigned short uh = __builtin_bit_cast(unsigned short, (__bf16)b);
    return (unsigned)ul | ((unsigned)uh << 16);
}

// key-block index for tile i (wave-uniform arithmetic, no arrays)
__device__ __forceinline__ int tile_kb(int e, int ch, int qb, int ra0, int ra1, int ra2, int i) {
    if (e >= 0) return ch * 8 + i;
    const int rnd = (i == 4) ? ra0 : ((i == 5) ? ra1 : ra2);
    if (qb == 1)        return (i < 3) ? i : ((i == 3) ? NB_ - 1 : rnd);
    if (qb == NB_ - 2)  return (i == 0) ? 0 : ((i < 4) ? 60 + i : rnd);
    // middle
    if (i == 0) return 0;
    if (i < 4)  return qb - 2 + i;
    if (i < 7)  return rnd;
    return NB_ - 1;
}

__global__ __launch_bounds__(256, 5)
void bigbird_mfma(const float* __restrict__ q,  const float* __restrict__ k,
                  const float* __restrict__ v,  const float* __restrict__ band_mask,
                  const float* __restrict__ from_mask, const float* __restrict__ to_mask,
                  const float* __restrict__ from_blocked, const float* __restrict__ to_blocked,
                  const int*   __restrict__ rand_attn,   float* __restrict__ out,
                  float* __restrict__ ws)
{
    // K staged in A-fragment-linear order: slot (f*2+dh), lane l holds 16B:
    //   K[16f + (l&15)][32dh + (l>>4)*8 + j], j=0..7   (bf16)
    // V staged in B-fragment-linear order: slot (nf*2+kh), lane l holds:
    //   V[32kh + (l>>4)*8 + j][nf*16 + (l&15)], j=0..7 (bf16)
    __shared__ int4 kf[2][8][64];   // 2 x 8 KB
    __shared__ int4 vf[2][8][64];   // 2 x 8 KB  -> total exactly 32768 B

    const int wg  = blockIdx.x;
    const int bh  = wg / PER_BH;
    const int idx = wg % PER_BH;
    const int h   = bh % H_;
    const int b   = bh / H_;
    int qb, e = -1, ch = 0;
    if (idx < 62)      { qb = idx + 1; }
    else if (idx < 70) { e = 0; ch = idx - 62; qb = 0; }
    else               { e = 1; ch = idx - 70; qb = NB_ - 1; }

    const int t  = threadIdx.x;
    const int l  = t & 63;
    const int w  = t >> 6;
    const int c  = l & 15;      // q index within wave strip
    const int hh = l >> 4;      // lane quarter

    // rand-attn indices (wave-uniform scalar loads)
    int ra0 = 0, ra1 = 0, ra2 = 0;
    int nkb;
    if (e >= 0) nkb = 8;
    else {
        const int* ra = rand_attn + ((b * H_ + h) * (NB_ - 2) + (qb - 1)) * R_;
        ra0 = ra[0]; ra1 = ra[1]; ra2 = ra[2];
        nkb = (qb == 1 || qb == NB_ - 2) ? 7 : 8;
    }

    // K staging geometry: thread owns K row rr, 16 cols at cc4*16
    const int rr  = t >> 2;
    const int cc4 = t & 3;
    const float* kbase = k + ((size_t)bh * M_ + rr) * 64 + cc4 * 16;
    const int kslot = (rr >> 4) * 2 + (cc4 >> 1);
    const int kr15  = rr & 15;
    const int kg0   = (cc4 & 1) * 2;

    // V staging geometry: thread owns 8 k-rows (oct8*8+j) x 2 d-cols (d0v, d0v+1)
    const int d0v  = (t & 31) * 2;
    const int oct8 = t >> 5;            // 0..7
    const float* vbase = v + (size_t)bh * M_ * 64 + (size_t)(oct8 * 8) * 64 + d0v;
    const int vslot = (d0v >> 4) * 2 + (oct8 >> 2);
    const int vidx  = (oct8 & 3) * 16 + (d0v & 15);

    // ---- Q B-fragments (held all kernel): lane holds Q[q0w + c][32dh + hh*8 + j]
    bf16x8 qf[2];
    {
        const float* qp = q + ((size_t)bh * M_ + (size_t)qb * 64 + w * 16 + c) * 64 + hh * 8;
        #pragma unroll
        for (int dh = 0; dh < 2; ++dh) {
            float4 a0 = *(const float4*)(qp + dh * 32);
            float4 a1 = *(const float4*)(qp + dh * 32 + 4);
            bf16x8 qv;
            qv[0] = bf16s(a0.x); qv[1] = bf16s(a0.y); qv[2] = bf16s(a0.z); qv[3] = bf16s(a0.w);
            qv[4] = bf16s(a1.x); qv[5] = bf16s(a1.y); qv[6] = bf16s(a1.z); qv[7] = bf16s(a1.w);
            qf[dh] = qv;
        }
    }

    const float fbv = from_blocked[(b * NB_ + qb) * 64 + (w * 16 + c)];

    float mrun = -INFINITY, lrun = 0.0f;   // mrun in log2 domain
    f32x4 O[4];
    #pragma unroll
    for (int nf = 0; nf < 4; ++nf) { O[nf][0] = 0.f; O[nf][1] = 0.f; O[nf][2] = 0.f; O[nf][3] = 0.f; }

    float4 kr0, kr1, kr2, kr3;
    float2 vr[8];

    // ---- prologue: tile 0 -> regs -> buf 0
    {
        const int kb0 = tile_kb(e, ch, qb, ra0, ra1, ra2, 0);
        const float4* kp4 = (const float4*)(kbase + (size_t)kb0 * 4096);
        kr0 = kp4[0]; kr1 = kp4[1]; kr2 = kp4[2]; kr3 = kp4[3];
        const float* vp = vbase + (size_t)kb0 * 4096;
        #pragma unroll
        for (int j = 0; j < 8; ++j) vr[j] = *(const float2*)(vp + j * 64);

        float kfl[16];
        kfl[0]=kr0.x; kfl[1]=kr0.y; kfl[2]=kr0.z; kfl[3]=kr0.w;
        kfl[4]=kr1.x; kfl[5]=kr1.y; kfl[6]=kr1.z; kfl[7]=kr1.w;
        kfl[8]=kr2.x; kfl[9]=kr2.y; kfl[10]=kr2.z; kfl[11]=kr2.w;
        kfl[12]=kr3.x; kfl[13]=kr3.y; kfl[14]=kr3.z; kfl[15]=kr3.w;
        bf16x8 o0, o1;
        #pragma unroll
        for (int j = 0; j < 8; ++j) { o0[j] = bf16s(kfl[j]); o1[j] = bf16s(kfl[8 + j]); }
        kf[0][kslot][kg0 * 16 + kr15]       = __builtin_bit_cast(int4, o0);
        kf[0][kslot][(kg0 + 1) * 16 + kr15] = __builtin_bit_cast(int4, o1);

        bf16x8 va, vb2;
        #pragma unroll
        for (int j = 0; j < 8; ++j) { va[j] = bf16s(vr[j].x); vb2[j] = bf16s(vr[j].y); }
        vf[0][vslot][vidx]     = __builtin_bit_cast(int4, va);
        vf[0][vslot][vidx + 1] = __builtin_bit_cast(int4, vb2);
    }
    __syncthreads();

    for (int it = 0; it < nkb; ++it) {
        const int cur = it & 1;
        const int kb = tile_kb(e, ch, qb, ra0, ra1, ra2, it);
        int mode = 0, boff = 0;
        if (e < 0) {
            if (qb == 1 || qb == NB_ - 2) { mode = (it >= 4) ? 2 : 0; }
            else {
                if (it >= 1 && it < 4)      { mode = 1; boff = (it - 1) * 64; }
                else if (it >= 4 && it < 7) { mode = 2; }
            }
        }

        // ---- issue global loads for tile it+1 (land under compute)
        if (it + 1 < nkb) {
            const int kbn = tile_kb(e, ch, qb, ra0, ra1, ra2, it + 1);
            const float4* kp4 = (const float4*)(kbase + (size_t)kbn * 4096);
            kr0 = kp4[0]; kr1 = kp4[1]; kr2 = kp4[2]; kr3 = kp4[3];
            const float* vp = vbase + (size_t)kbn * 4096;
            #pragma unroll
            for (int j = 0; j < 8; ++j) vr[j] = *(const float2*)(vp + j * 64);
        }

        // ---- S^T = K * Q^T : lane holds S[q = c][k = 16f + 4hh + r]
        f32x4 sf[4];
        #pragma unroll
        for (int f = 0; f < 4; ++f) { sf[f][0]=0.f; sf[f][1]=0.f; sf[f][2]=0.f; sf[f][3]=0.f; }
        #pragma unroll
        for (int f = 0; f < 4; ++f) {
            sf[f] = __builtin_amdgcn_mfma_f32_16x16x32_bf16(
                        __builtin_bit_cast(bf16x8, kf[cur][f * 2 + 0][l]), qf[0], sf[f], 0, 0, 0);
            sf[f] = __builtin_amdgcn_mfma_f32_16x16x32_bf16(
                        __builtin_bit_cast(bf16x8, kf[cur][f * 2 + 1][l]), qf[1], sf[f], 0, 0, 0);
        }

        // ---- masks (vectorized float4 loads)
        float msk[4][4];
        if (mode == 0) {
            const float* mp = to_mask + b * M_ + kb * 64 + 4 * hh;
            #pragma unroll
            for (int f = 0; f < 4; ++f) {
                float4 mv = *(const float4*)(mp + 16 * f);
                msk[f][0] = mv.x; msk[f][1] = mv.y; msk[f][2] = mv.z; msk[f][3] = mv.w;
            }
        } else if (mode == 1) {
            const float* mp = band_mask + (((size_t)b * (NB_ - 4) + (qb - 2)) * 64 + (w * 16 + c)) * 192 + boff + 4 * hh;
            #pragma unroll
            for (int f = 0; f < 4; ++f) {
                float4 mv = *(const float4*)(mp + 16 * f);
                msk[f][0] = mv.x; msk[f][1] = mv.y; msk[f][2] = mv.z; msk[f][3] = mv.w;
            }
        } else {
            const float* mp = to_blocked + (b * NB_ + kb) * 64 + 4 * hh;
            #pragma unroll
            for (int f = 0; f < 4; ++f) {
                float4 mv = *(const float4*)(mp + 16 * f);
                msk[f][0] = fbv * mv.x; msk[f][1] = fbv * mv.y;
                msk[f][2] = fbv * mv.z; msk[f][3] = fbv * mv.w;
            }
        }

        // ---- scale + mask + online softmax, log2 domain (lane-local + 2 shfl_xor)
        float p[4][4];
        float tmax = -INFINITY;
        #pragma unroll
        for (int f = 0; f < 4; ++f) {
            #pragma unroll
            for (int r = 0; r < 4; ++r) {
                const float s = sf[f][r] * SCALE2 + (1.0f - msk[f][r]) * NEG2;
                p[f][r] = s;
                tmax = fmaxf(tmax, s);
            }
        }
        tmax = fmaxf(tmax, __shfl_xor(tmax, 16));
        tmax = fmaxf(tmax, __shfl_xor(tmax, 32));
        const float mnew = fmaxf(mrun, tmax);
        const float fs = exp2f(mrun - mnew);   // 0 on first tile
        float sum = 0.0f;
        #pragma unroll
        for (int f = 0; f < 4; ++f) {
            #pragma unroll
            for (int r = 0; r < 4; ++r) { p[f][r] = exp2f(p[f][r] - mnew); sum += p[f][r]; }
        }
        sum += __shfl_xor(sum, 16);
        sum += __shfl_xor(sum, 32);
        lrun = lrun * fs + sum;
        mrun = mnew;

        // ---- rescale O (rows are q = 4hh + r -> fetch fs from lane 4hh+r)
        const float fr0 = __shfl(fs, hh * 4 + 0);
        const float fr1 = __shfl(fs, hh * 4 + 1);
        const float fr2 = __shfl(fs, hh * 4 + 2);
        const float fr3 = __shfl(fs, hh * 4 + 3);
        #pragma unroll
        for (int nf = 0; nf < 4; ++nf) {
            O[nf][0] *= fr0; O[nf][1] *= fr1; O[nf][2] *= fr2; O[nf][3] *= fr3;
        }

        // ---- P -> bf16, redistribute to PV A-frag layout (in-wave shuffles)
        unsigned pks[4][2];
        #pragma unroll
        for (int f = 0; f < 4; ++f) {
            pks[f][0] = pack_bf16(p[f][0], p[f][1]);
            pks[f][1] = pack_bf16(p[f][2], p[f][3]);
        }
        #pragma unroll
        for (int kh = 0; kh < 2; ++kh) {
            unsigned ad[4];
            #pragma unroll
            for (int wq = 0; wq < 4; ++wq) {
                const int pos = wq >> 1, ww = wq & 1;
                const int src = c + 16 * ((2 * hh + pos) & 3);
                const unsigned x = (unsigned)__shfl((int)pks[2 * kh][ww], src);
                const unsigned y = (unsigned)__shfl((int)pks[2 * kh + 1][ww], src);
                ad[wq] = (hh & 2) ? y : x;
            }
            const uint4 adv = make_uint4(ad[0], ad[1], ad[2], ad[3]);
            const bf16x8 pa = __builtin_bit_cast(bf16x8, adv);
            #pragma unroll
            for (int nf = 0; nf < 4; ++nf) {
                O[nf] = __builtin_amdgcn_mfma_f32_16x16x32_bf16(
                            pa, __builtin_bit_cast(bf16x8, vf[cur][nf * 2 + kh][l]), O[nf], 0, 0, 0);
            }
        }

        // ---- write tile it+1 into the other buffer (waits on global loads)
        if (it + 1 < nkb) {
            const int nxt = cur ^ 1;
            float kfl[16];
            kfl[0]=kr0.x; kfl[1]=kr0.y; kfl[2]=kr0.z; kfl[3]=kr0.w;
            kfl[4]=kr1.x; kfl[5]=kr1.y; kfl[6]=kr1.z; kfl[7]=kr1.w;
            kfl[8]=kr2.x; kfl[9]=kr2.y; kfl[10]=kr2.z; kfl[11]=kr2.w;
            kfl[12]=kr3.x; kfl[13]=kr3.y; kfl[14]=kr3.z; kfl[15]=kr3.w;
            bf16x8 o0, o1;
            #pragma unroll
            for (int j = 0; j < 8; ++j) { o0[j] = bf16s(kfl[j]); o1[j] = bf16s(kfl[8 + j]); }
            kf[nxt][kslot][kg0 * 16 + kr15]       = __builtin_bit_cast(int4, o0);
            kf[nxt][kslot][(kg0 + 1) * 16 + kr15] = __builtin_bit_cast(int4, o1);

            bf16x8 va, vb2;
            #pragma unroll
            for (int j = 0; j < 8; ++j) { va[j] = bf16s(vr[j].x); vb2[j] = bf16s(vr[j].y); }
            vf[nxt][vslot][vidx]     = __builtin_bit_cast(int4, va);
            vf[nxt][vslot][vidx + 1] = __builtin_bit_cast(int4, vb2);
        }
        __syncthreads();
    }

    // ---- epilogue: O rows are q_local = w*16 + 4hh + r, cols d = nf*16 + c
    if (e < 0) {
        #pragma unroll
        for (int r = 0; r < 4; ++r) {
            const float lr  = __shfl(lrun, hh * 4 + r);
            const int   qg  = qb * 64 + w * 16 + hh * 4 + r;
            const float fmv = from_mask[b * M_ + qg];
            const float scl = fmv / lr;
            float* op = out + (((size_t)b * M_ + qg) * H_ + h) * 64 + c;
            #pragma unroll
            for (int nf = 0; nf < 4; ++nf) op[nf * 16] = O[nf][r] * scl;
        }
    } else {
        const int pe = (bh * 2 + e) * 8 + ch;
        #pragma unroll
        for (int r = 0; r < 4; ++r) {
            const int qlocal = w * 16 + hh * 4 + r;
            float* pa = ws + PACC_OFF + ((size_t)pe * 64 + qlocal) * 64 + c;
            #pragma unroll
            for (int nf = 0; nf < 4; ++nf) pa[nf * 16] = O[nf][r];
        }
        if (hh == 0) {
            ws[PM_OFF + pe * 64 + w * 16 + c] = mrun;   // log2 domain
            ws[PL_OFF + pe * 64 + w * 16 + c] = lrun;
        }
    }
}

// Combine the 8 partials for each edge q-block row (m in log2 domain).
__global__ __launch_bounds__(256)
void bigbird_combine(const float* __restrict__ ws, const float* __restrict__ from_mask,
                     float* __restrict__ out)
{
    const int g  = blockIdx.x;          // bh*2 + e
    const int e  = g & 1;
    const int bh = g >> 1;
    const int h  = bh % H_;
    const int b  = bh / H_;
    const int qb = e ? NB_ - 1 : 0;

    const int t  = threadIdx.x;
    const int r  = t >> 2;
    const int dq = (t & 3) * 16;

    float mc[8], lc[8];
    float m = -INFINITY;
    #pragma unroll
    for (int c = 0; c < 8; ++c) {
        mc[c] = ws[PM_OFF + (g * 8 + c) * 64 + r];
        lc[c] = ws[PL_OFF + (g * 8 + c) * 64 + r];
        m = fmaxf(m, mc[c]);
    }
    float l = 0.0f;
    float acc[16];
    #pragma unroll
    for (int j = 0; j < 16; ++j) acc[j] = 0.0f;
    #pragma unroll
    for (int c = 0; c < 8; ++c) {
        const float sc = exp2f(mc[c] - m);
        l += lc[c] * sc;
        const float4* pa = (const float4*)(ws + PACC_OFF + ((size_t)(g * 8 + c) * 64 + r) * 64 + dq);
        #pragma unroll
        for (int j4 = 0; j4 < 4; ++j4) {
            float4 av = pa[j4];
            acc[j4 * 4 + 0] += sc * av.x;
            acc[j4 * 4 + 1] += sc * av.y;
            acc[j4 * 4 + 2] += sc * av.z;
            acc[j4 * 4 + 3] += sc * av.w;
        }
    }
    const float fm = from_mask[b * M_ + qb * 64 + r];
    const float s  = fm / l;
    float* op = out + (((size_t)b * M_ + qb * 64 + r) * H_ + h) * 64 + dq;
    #pragma unroll
    for (int j4 = 0; j4 < 4; ++j4) {
        float4 o;
        o.x = acc[j4 * 4 + 0] * s; o.y = acc[j4 * 4 + 1] * s;
        o.z = acc[j4 * 4 + 2] * s; o.w = acc[j4 * 4 + 3] * s;
        *(float4*)(op + j4 * 4) = o;
    }
}

extern "C" void kernel_launch(void* const* d_in, const int* in_sizes, int n_in,
                              void* d_out, int out_size, void* d_ws, size_t ws_size,
                              hipStream_t stream) {
    const float* q  = (const float*)d_in[0];
    const float* k  = (const float*)d_in[1];
    const float* v  = (const float*)d_in[2];
    const float* bm = (const float*)d_in[3];
    const float* fm = (const float*)d_in[4];
    const float* tm = (const float*)d_in[5];
    const float* fb = (const float*)d_in[6];
    const float* tb = (const float*)d_in[7];
    const int*   ra = (const int*)d_in[8];
    float* o  = (float*)d_out;
    float* ws = (float*)d_ws;

    hipLaunchKernelGGL(bigbird_mfma, dim3(B_ * H_ * PER_BH), dim3(256), 0, stream,
                       q, k, v, bm, fm, tm, fb, tb, ra, o, ws);
    hipLaunchKernelGGL(bigbird_combine, dim3(B_ * H_ * 2), dim3(256), 0, stream,
                       ws, fm, o);
}

// Round 7
// 105.095 us; speedup vs baseline: 1.8882x; 1.8882x over previous
//
#include <hip/hip_runtime.h>
#include <math.h>

// BigBird block-sparse attention, bf16 MFMA, double-buffered LDS (1 barrier/tile),
// LDS = exactly 32 KB -> 5 blocks/CU; tile list in registers; exp2-domain softmax.
// B=2 H=16 M=N=4096 D=64 WM=WN=64 R=3 nb=64.
constexpr int B_  = 2;
constexpr int H_  = 16;
constexpr int M_  = 4096;
constexpr int NB_ = 64;
constexpr int R_  = 3;
constexpr float LOG2E  = 1.44269504089f;
constexpr float SCALE2 = 0.125f * LOG2E;          // (1/sqrt(64)) * log2(e)
constexpr float NEG2   = -10000.0f * LOG2E;

constexpr int PER_BH = 62 + 16;             // 62 middle + 2 edges * 8 chunks
constexpr int PACC_OFF = 0;                                  // [BH][2][8][64][64]
constexpr int PM_OFF   = B_ * H_ * 2 * 8 * 64 * 64;          // [BH][2][8][64]
constexpr int PL_OFF   = PM_OFF + B_ * H_ * 2 * 8 * 64;

typedef short bf16x8 __attribute__((ext_vector_type(8)));   // 8 bf16 in 4 VGPRs
typedef float f32x4  __attribute__((ext_vector_type(4)));

__device__ __forceinline__ short bf16s(float x) {
    return __builtin_bit_cast(short, (__bf16)x);
}
__device__ __forceinline__ unsigned pack_bf16(float a, float b) {
    unsigned short ul = __builtin_bit_cast(unsigned short, (__bf16)a);
    unsigned short uh = __builtin_bit_cast(unsigned short, (__bf16)b);
    return (unsigned)ul | ((unsigned)uh << 16);
}

// key-block index for tile i (wave-uniform arithmetic, no arrays)
__device__ __forceinline__ int tile_kb(int e, int ch, int qb, int ra0, int ra1, int ra2, int i) {
    if (e >= 0) return ch * 8 + i;
    const int rnd = (i == 4) ? ra0 : ((i == 5) ? ra1 : ra2);
    if (qb == 1)        return (i < 3) ? i : ((i == 3) ? NB_ - 1 : rnd);
    if (qb == NB_ - 2)  return (i == 0) ? 0 : ((i < 4) ? 60 + i : rnd);
    // middle
    if (i == 0) return 0;
    if (i < 4)  return qb - 2 + i;
    if (i < 7)  return rnd;
    return NB_ - 1;
}

__global__ __launch_bounds__(256, 4)
void bigbird_mfma(const float* __restrict__ q,  const float* __restrict__ k,
                  const float* __restrict__ v,  const float* __restrict__ band_mask,
                  const float* __restrict__ from_mask, const float* __restrict__ to_mask,
                  const float* __restrict__ from_blocked, const float* __restrict__ to_blocked,
                  const int*   __restrict__ rand_attn,   float* __restrict__ out,
                  float* __restrict__ ws)
{
    // K staged in A-fragment-linear order: slot (f*2+dh), lane l holds 16B:
    //   K[16f + (l&15)][32dh + (l>>4)*8 + j], j=0..7   (bf16)
    // V staged in B-fragment-linear order: slot (nf*2+kh), lane l holds:
    //   V[32kh + (l>>4)*8 + j][nf*16 + (l&15)], j=0..7 (bf16)
    __shared__ int4 kf[2][8][64];   // 2 x 8 KB
    __shared__ int4 vf[2][8][64];   // 2 x 8 KB  -> total exactly 32768 B

    const int wg  = blockIdx.x;
    const int bh  = wg / PER_BH;
    const int idx = wg % PER_BH;
    const int h   = bh % H_;
    const int b   = bh / H_;
    int qb, e = -1, ch = 0;
    if (idx < 62)      { qb = idx + 1; }
    else if (idx < 70) { e = 0; ch = idx - 62; qb = 0; }
    else               { e = 1; ch = idx - 70; qb = NB_ - 1; }

    const int t  = threadIdx.x;
    const int l  = t & 63;
    const int w  = t >> 6;
    const int c  = l & 15;      // q index within wave strip
    const int hh = l >> 4;      // lane quarter

    // rand-attn indices (wave-uniform scalar loads)
    int ra0 = 0, ra1 = 0, ra2 = 0;
    int nkb;
    if (e >= 0) nkb = 8;
    else {
        const int* ra = rand_attn + ((b * H_ + h) * (NB_ - 2) + (qb - 1)) * R_;
        ra0 = ra[0]; ra1 = ra[1]; ra2 = ra[2];
        nkb = (qb == 1 || qb == NB_ - 2) ? 7 : 8;
    }

    // K staging geometry: thread owns K row rr, 16 cols at cc4*16
    const int rr  = t >> 2;
    const int cc4 = t & 3;
    const float* kbase = k + ((size_t)bh * M_ + rr) * 64 + cc4 * 16;
    const int kslot = (rr >> 4) * 2 + (cc4 >> 1);
    const int kr15  = rr & 15;
    const int kg0   = (cc4 & 1) * 2;

    // V staging geometry: thread owns 8 k-rows (oct8*8+j) x 2 d-cols (d0v, d0v+1)
    const int d0v  = (t & 31) * 2;
    const int oct8 = t >> 5;            // 0..7
    const float* vbase = v + (size_t)bh * M_ * 64 + (size_t)(oct8 * 8) * 64 + d0v;
    const int vslot = (d0v >> 4) * 2 + (oct8 >> 2);
    const int vidx  = (oct8 & 3) * 16 + (d0v & 15);

    // ---- Q B-fragments (held all kernel): lane holds Q[q0w + c][32dh + hh*8 + j]
    bf16x8 qf[2];
    {
        const float* qp = q + ((size_t)bh * M_ + (size_t)qb * 64 + w * 16 + c) * 64 + hh * 8;
        #pragma unroll
        for (int dh = 0; dh < 2; ++dh) {
            float4 a0 = *(const float4*)(qp + dh * 32);
            float4 a1 = *(const float4*)(qp + dh * 32 + 4);
            bf16x8 qv;
            qv[0] = bf16s(a0.x); qv[1] = bf16s(a0.y); qv[2] = bf16s(a0.z); qv[3] = bf16s(a0.w);
            qv[4] = bf16s(a1.x); qv[5] = bf16s(a1.y); qv[6] = bf16s(a1.z); qv[7] = bf16s(a1.w);
            qf[dh] = qv;
        }
    }

    const float fbv = from_blocked[(b * NB_ + qb) * 64 + (w * 16 + c)];

    float mrun = -INFINITY, lrun = 0.0f;   // mrun in log2 domain
    f32x4 O[4];
    #pragma unroll
    for (int nf = 0; nf < 4; ++nf) { O[nf][0] = 0.f; O[nf][1] = 0.f; O[nf][2] = 0.f; O[nf][3] = 0.f; }

    float4 kr0, kr1, kr2, kr3;
    float2 vr[8];

    // ---- prologue: tile 0 -> regs -> buf 0
    {
        const int kb0 = tile_kb(e, ch, qb, ra0, ra1, ra2, 0);
        const float4* kp4 = (const float4*)(kbase + (size_t)kb0 * 4096);
        kr0 = kp4[0]; kr1 = kp4[1]; kr2 = kp4[2]; kr3 = kp4[3];
        const float* vp = vbase + (size_t)kb0 * 4096;
        #pragma unroll
        for (int j = 0; j < 8; ++j) vr[j] = *(const float2*)(vp + j * 64);

        float kfl[16];
        kfl[0]=kr0.x; kfl[1]=kr0.y; kfl[2]=kr0.z; kfl[3]=kr0.w;
        kfl[4]=kr1.x; kfl[5]=kr1.y; kfl[6]=kr1.z; kfl[7]=kr1.w;
        kfl[8]=kr2.x; kfl[9]=kr2.y; kfl[10]=kr2.z; kfl[11]=kr2.w;
        kfl[12]=kr3.x; kfl[13]=kr3.y; kfl[14]=kr3.z; kfl[15]=kr3.w;
        bf16x8 o0, o1;
        #pragma unroll
        for (int j = 0; j < 8; ++j) { o0[j] = bf16s(kfl[j]); o1[j] = bf16s(kfl[8 + j]); }
        kf[0][kslot][kg0 * 16 + kr15]       = __builtin_bit_cast(int4, o0);
        kf[0][kslot][(kg0 + 1) * 16 + kr15] = __builtin_bit_cast(int4, o1);

        bf16x8 va, vb2;
        #pragma unroll
        for (int j = 0; j < 8; ++j) { va[j] = bf16s(vr[j].x); vb2[j] = bf16s(vr[j].y); }
        vf[0][vslot][vidx]     = __builtin_bit_cast(int4, va);
        vf[0][vslot][vidx + 1] = __builtin_bit_cast(int4, vb2);
    }
    __syncthreads();

    for (int it = 0; it < nkb; ++it) {
        const int cur = it & 1;
        const int kb = tile_kb(e, ch, qb, ra0, ra1, ra2, it);
        int mode = 0, boff = 0;
        if (e < 0) {
            if (qb == 1 || qb == NB_ - 2) { mode = (it >= 4) ? 2 : 0; }
            else {
                if (it >= 1 && it < 4)      { mode = 1; boff = (it - 1) * 64; }
                else if (it >= 4 && it < 7) { mode = 2; }
            }
        }

        // ---- issue global loads for tile it+1 (land under compute)
        if (it + 1 < nkb) {
            const int kbn = tile_kb(e, ch, qb, ra0, ra1, ra2, it + 1);
            const float4* kp4 = (const float4*)(kbase + (size_t)kbn * 4096);
            kr0 = kp4[0]; kr1 = kp4[1]; kr2 = kp4[2]; kr3 = kp4[3];
            const float* vp = vbase + (size_t)kbn * 4096;
            #pragma unroll
            for (int j = 0; j < 8; ++j) vr[j] = *(const float2*)(vp + j * 64);
        }

        // ---- S^T = K * Q^T : lane holds S[q = c][k = 16f + 4hh + r]
        f32x4 sf[4];
        #pragma unroll
        for (int f = 0; f < 4; ++f) { sf[f][0]=0.f; sf[f][1]=0.f; sf[f][2]=0.f; sf[f][3]=0.f; }
        #pragma unroll
        for (int f = 0; f < 4; ++f) {
            sf[f] = __builtin_amdgcn_mfma_f32_16x16x32_bf16(
                        __builtin_bit_cast(bf16x8, kf[cur][f * 2 + 0][l]), qf[0], sf[f], 0, 0, 0);
            sf[f] = __builtin_amdgcn_mfma_f32_16x16x32_bf16(
                        __builtin_bit_cast(bf16x8, kf[cur][f * 2 + 1][l]), qf[1], sf[f], 0, 0, 0);
        }

        // ---- masks (vectorized float4 loads)
        float msk[4][4];
        if (mode == 0) {
            const float* mp = to_mask + b * M_ + kb * 64 + 4 * hh;
            #pragma unroll
            for (int f = 0; f < 4; ++f) {
                float4 mv = *(const float4*)(mp + 16 * f);
                msk[f][0] = mv.x; msk[f][1] = mv.y; msk[f][2] = mv.z; msk[f][3] = mv.w;
            }
        } else if (mode == 1) {
            const float* mp = band_mask + (((size_t)b * (NB_ - 4) + (qb - 2)) * 64 + (w * 16 + c)) * 192 + boff + 4 * hh;
            #pragma unroll
            for (int f = 0; f < 4; ++f) {
                float4 mv = *(const float4*)(mp + 16 * f);
                msk[f][0] = mv.x; msk[f][1] = mv.y; msk[f][2] = mv.z; msk[f][3] = mv.w;
            }
        } else {
            const float* mp = to_blocked + (b * NB_ + kb) * 64 + 4 * hh;
            #pragma unroll
            for (int f = 0; f < 4; ++f) {
                float4 mv = *(const float4*)(mp + 16 * f);
                msk[f][0] = fbv * mv.x; msk[f][1] = fbv * mv.y;
                msk[f][2] = fbv * mv.z; msk[f][3] = fbv * mv.w;
            }
        }

        // ---- scale + mask + online softmax, log2 domain (lane-local + 2 shfl_xor)
        float p[4][4];
        float tmax = -INFINITY;
        #pragma unroll
        for (int f = 0; f < 4; ++f) {
            #pragma unroll
            for (int r = 0; r < 4; ++r) {
                const float s = sf[f][r] * SCALE2 + (1.0f - msk[f][r]) * NEG2;
                p[f][r] = s;
                tmax = fmaxf(tmax, s);
            }
        }
        tmax = fmaxf(tmax, __shfl_xor(tmax, 16));
        tmax = fmaxf(tmax, __shfl_xor(tmax, 32));
        const float mnew = fmaxf(mrun, tmax);
        const float fs = exp2f(mrun - mnew);   // 0 on first tile
        float sum = 0.0f;
        #pragma unroll
        for (int f = 0; f < 4; ++f) {
            #pragma unroll
            for (int r = 0; r < 4; ++r) { p[f][r] = exp2f(p[f][r] - mnew); sum += p[f][r]; }
        }
        sum += __shfl_xor(sum, 16);
        sum += __shfl_xor(sum, 32);
        lrun = lrun * fs + sum;
        mrun = mnew;

        // ---- rescale O (rows are q = 4hh + r -> fetch fs from lane 4hh+r)
        const float fr0 = __shfl(fs, hh * 4 + 0);
        const float fr1 = __shfl(fs, hh * 4 + 1);
        const float fr2 = __shfl(fs, hh * 4 + 2);
        const float fr3 = __shfl(fs, hh * 4 + 3);
        #pragma unroll
        for (int nf = 0; nf < 4; ++nf) {
            O[nf][0] *= fr0; O[nf][1] *= fr1; O[nf][2] *= fr2; O[nf][3] *= fr3;
        }

        // ---- P -> bf16, redistribute to PV A-frag layout (in-wave shuffles)
        unsigned pks[4][2];
        #pragma unroll
        for (int f = 0; f < 4; ++f) {
            pks[f][0] = pack_bf16(p[f][0], p[f][1]);
            pks[f][1] = pack_bf16(p[f][2], p[f][3]);
        }
        #pragma unroll
        for (int kh = 0; kh < 2; ++kh) {
            unsigned ad[4];
            #pragma unroll
            for (int wq = 0; wq < 4; ++wq) {
                const int pos = wq >> 1, ww = wq & 1;
                const int src = c + 16 * ((2 * hh + pos) & 3);
                const unsigned x = (unsigned)__shfl((int)pks[2 * kh][ww], src);
                const unsigned y = (unsigned)__shfl((int)pks[2 * kh + 1][ww], src);
                ad[wq] = (hh & 2) ? y : x;
            }
            const uint4 adv = make_uint4(ad[0], ad[1], ad[2], ad[3]);
            const bf16x8 pa = __builtin_bit_cast(bf16x8, adv);
            #pragma unroll
            for (int nf = 0; nf < 4; ++nf) {
                O[nf] = __builtin_amdgcn_mfma_f32_16x16x32_bf16(
                            pa, __builtin_bit_cast(bf16x8, vf[cur][nf * 2 + kh][l]), O[nf], 0, 0, 0);
            }
        }

        // ---- write tile it+1 into the other buffer (waits on global loads)
        if (it + 1 < nkb) {
            const int nxt = cur ^ 1;
            float kfl[16];
            kfl[0]=kr0.x; kfl[1]=kr0.y; kfl[2]=kr0.z; kfl[3]=kr0.w;
            kfl[4]=kr1.x; kfl[5]=kr1.y; kfl[6]=kr1.z; kfl[7]=kr1.w;
            kfl[8]=kr2.x; kfl[9]=kr2.y; kfl[10]=kr2.z; kfl[11]=kr2.w;
            kfl[12]=kr3.x; kfl[13]=kr3.y; kfl[14]=kr3.z; kfl[15]=kr3.w;
            bf16x8 o0, o1;
            #pragma unroll
            for (int j = 0; j < 8; ++j) { o0[j] = bf16s(kfl[j]); o1[j] = bf16s(kfl[8 + j]); }
            kf[nxt][kslot][kg0 * 16 + kr15]       = __builtin_bit_cast(int4, o0);
            kf[nxt][kslot][(kg0 + 1) * 16 + kr15] = __builtin_bit_cast(int4, o1);

            bf16x8 va, vb2;
            #pragma unroll
            for (int j = 0; j < 8; ++j) { va[j] = bf16s(vr[j].x); vb2[j] = bf16s(vr[j].y); }
            vf[nxt][vslot][vidx]     = __builtin_bit_cast(int4, va);
            vf[nxt][vslot][vidx + 1] = __builtin_bit_cast(int4, vb2);
        }
        __syncthreads();
    }

    // ---- epilogue: O rows are q_local = w*16 + 4hh + r, cols d = nf*16 + c
    if (e < 0) {
        #pragma unroll
        for (int r = 0; r < 4; ++r) {
            const float lr  = __shfl(lrun, hh * 4 + r);
            const int   qg  = qb * 64 + w * 16 + hh * 4 + r;
            const float fmv = from_mask[b * M_ + qg];
            const float scl = fmv / lr;
            float* op = out + (((size_t)b * M_ + qg) * H_ + h) * 64 + c;
            #pragma unroll
            for (int nf = 0; nf < 4; ++nf) op[nf * 16] = O[nf][r] * scl;
        }
    } else {
        const int pe = (bh * 2 + e) * 8 + ch;
        #pragma unroll
        for (int r = 0; r < 4; ++r) {
            const int qlocal = w * 16 + hh * 4 + r;
            float* pa = ws + PACC_OFF + ((size_t)pe * 64 + qlocal) * 64 + c;
            #pragma unroll
            for (int nf = 0; nf < 4; ++nf) pa[nf * 16] = O[nf][r];
        }
        if (hh == 0) {
            ws[PM_OFF + pe * 64 + w * 16 + c] = mrun;   // log2 domain
            ws[PL_OFF + pe * 64 + w * 16 + c] = lrun;
        }
    }
}

// Combine the 8 partials for each edge q-block row (m in log2 domain).
__global__ __launch_bounds__(256)
void bigbird_combine(const float* __restrict__ ws, const float* __restrict__ from_mask,
                     float* __restrict__ out)
{
    const int g  = blockIdx.x;          // bh*2 + e
    const int e  = g & 1;
    const int bh = g >> 1;
    const int h  = bh % H_;
    const int b  = bh / H_;
    const int qb = e ? NB_ - 1 : 0;

    const int t  = threadIdx.x;
    const int r  = t >> 2;
    const int dq = (t & 3) * 16;

    float mc[8], lc[8];
    float m = -INFINITY;
    #pragma unroll
    for (int c = 0; c < 8; ++c) {
        mc[c] = ws[PM_OFF + (g * 8 + c) * 64 + r];
        lc[c] = ws[PL_OFF + (g * 8 + c) * 64 + r];
        m = fmaxf(m, mc[c]);
    }
    float l = 0.0f;
    float acc[16];
    #pragma unroll
    for (int j = 0; j < 16; ++j) acc[j] = 0.0f;
    #pragma unroll
    for (int c = 0; c < 8; ++c) {
        const float sc = exp2f(mc[c] - m);
        l += lc[c] * sc;
        const float4* pa = (const float4*)(ws + PACC_OFF + ((size_t)(g * 8 + c) * 64 + r) * 64 + dq);
        #pragma unroll
        for (int j4 = 0; j4 < 4; ++j4) {
            float4 av = pa[j4];
            acc[j4 * 4 + 0] += sc * av.x;
            acc[j4 * 4 + 1] += sc * av.y;
            acc[j4 * 4 + 2] += sc * av.z;
            acc[j4 * 4 + 3] += sc * av.w;
        }
    }
    const float fm = from_mask[b * M_ + qb * 64 + r];
    const float s  = fm / l;
    float* op = out + (((size_t)b * M_ + qb * 64 + r) * H_ + h) * 64 + dq;
    #pragma unroll
    for (int j4 = 0; j4 < 4; ++j4) {
        float4 o;
        o.x = acc[j4 * 4 + 0] * s; o.y = acc[j4 * 4 + 1] * s;
        o.z = acc[j4 * 4 + 2] * s; o.w = acc[j4 * 4 + 3] * s;
        *(float4*)(op + j4 * 4) = o;
    }
}

extern "C" void kernel_launch(void* const* d_in, const int* in_sizes, int n_in,
                              void* d_out, int out_size, void* d_ws, size_t ws_size,
                              hipStream_t stream) {
    const float* q  = (const float*)d_in[0];
    const float* k  = (const float*)d_in[1];
    const float* v  = (const float*)d_in[2];
    const float* bm = (const float*)d_in[3];
    const float* fm = (const float*)d_in[4];
    const float* tm = (const float*)d_in[5];
    const float* fb = (const float*)d_in[6];
    const float* tb = (const float*)d_in[7];
    const int*   ra = (const int*)d_in[8];
    float* o  = (float*)d_out;
    float* ws = (float*)d_ws;

    hipLaunchKernelGGL(bigbird_mfma, dim3(B_ * H_ * PER_BH), dim3(256), 0, stream,
                       q, k, v, bm, fm, tm, fb, tb, ra, o, ws);
    hipLaunchKernelGGL(bigbird_combine, dim3(B_ * H_ * 2), dim3(256), 0, stream,
                       ws, fm, o);
}

// Round 8
// 92.427 us; speedup vs baseline: 2.1470x; 1.1371x over previous
//
#include <hip/hip_runtime.h>
#include <math.h>

// BigBird block-sparse attention, bf16 MFMA, double-buffered LDS (1 barrier/tile),
// XCD-aware block swizzle (each (b,h)'s 78 blocks -> one XCD's L2),
// setprio around MFMA clusters, loads issued before the barrier.
// B=2 H=16 M=N=4096 D=64 WM=WN=64 R=3 nb=64.
constexpr int B_  = 2;
constexpr int H_  = 16;
constexpr int M_  = 4096;
constexpr int NB_ = 64;
constexpr int R_  = 3;
constexpr float LOG2E  = 1.44269504089f;
constexpr float SCALE2 = 0.125f * LOG2E;          // (1/sqrt(64)) * log2(e)
constexpr float NEG2   = -10000.0f * LOG2E;

constexpr int PER_BH = 62 + 16;             // 62 middle + 2 edges * 8 chunks
constexpr int NWG    = B_ * H_ * PER_BH;    // 2496 = 8 * 312
constexpr int PACC_OFF = 0;                                  // [BH][2][8][64][64]
constexpr int PM_OFF   = B_ * H_ * 2 * 8 * 64 * 64;          // [BH][2][8][64]
constexpr int PL_OFF   = PM_OFF + B_ * H_ * 2 * 8 * 64;

typedef short bf16x8 __attribute__((ext_vector_type(8)));   // 8 bf16 in 4 VGPRs
typedef float f32x4  __attribute__((ext_vector_type(4)));

__device__ __forceinline__ short bf16s(float x) {
    return __builtin_bit_cast(short, (__bf16)x);
}
__device__ __forceinline__ unsigned pack_bf16(float a, float b) {
    unsigned short ul = __builtin_bit_cast(unsigned short, (__bf16)a);
    unsigned short uh = __builtin_bit_cast(unsigned short, (__bf16)b);
    return (unsigned)ul | ((unsigned)uh << 16);
}

// key-block index for tile i (wave-uniform arithmetic, no arrays)
__device__ __forceinline__ int tile_kb(int e, int ch, int qb, int ra0, int ra1, int ra2, int i) {
    if (e >= 0) return ch * 8 + i;
    const int rnd = (i == 4) ? ra0 : ((i == 5) ? ra1 : ra2);
    if (qb == 1)        return (i < 3) ? i : ((i == 3) ? NB_ - 1 : rnd);
    if (qb == NB_ - 2)  return (i == 0) ? 0 : ((i < 4) ? 60 + i : rnd);
    // middle
    if (i == 0) return 0;
    if (i < 4)  return qb - 2 + i;
    if (i < 7)  return rnd;
    return NB_ - 1;
}

__global__ __launch_bounds__(256, 4)
void bigbird_mfma(const float* __restrict__ q,  const float* __restrict__ k,
                  const float* __restrict__ v,  const float* __restrict__ band_mask,
                  const float* __restrict__ from_mask, const float* __restrict__ to_mask,
                  const float* __restrict__ from_blocked, const float* __restrict__ to_blocked,
                  const int*   __restrict__ rand_attn,   float* __restrict__ out,
                  float* __restrict__ ws)
{
    // K staged in A-fragment-linear order: slot (f*2+dh), lane l holds 16B:
    //   K[16f + (l&15)][32dh + (l>>4)*8 + j], j=0..7   (bf16)
    // V staged in B-fragment-linear order: slot (nf*2+kh), lane l holds:
    //   V[32kh + (l>>4)*8 + j][nf*16 + (l&15)], j=0..7 (bf16)
    __shared__ int4 kf[2][8][64];   // 2 x 8 KB
    __shared__ int4 vf[2][8][64];   // 2 x 8 KB  -> total exactly 32768 B

    // XCD-aware swizzle: consecutive logical blocks (same (b,h)) -> same XCD.
    // NWG = 2496 = 8 * 312; 312 = exactly 4 bh-groups of PER_BH=78.
    const int wg  = (blockIdx.x & 7) * (NWG / 8) + (blockIdx.x >> 3);
    const int bh  = wg / PER_BH;
    const int idx = wg % PER_BH;
    const int h   = bh % H_;
    const int b   = bh / H_;
    int qb, e = -1, ch = 0;
    if (idx < 62)      { qb = idx + 1; }
    else if (idx < 70) { e = 0; ch = idx - 62; qb = 0; }
    else               { e = 1; ch = idx - 70; qb = NB_ - 1; }

    const int t  = threadIdx.x;
    const int l  = t & 63;
    const int w  = t >> 6;
    const int c  = l & 15;      // q index within wave strip
    const int hh = l >> 4;      // lane quarter

    // rand-attn indices (wave-uniform scalar loads)
    int ra0 = 0, ra1 = 0, ra2 = 0;
    int nkb;
    if (e >= 0) nkb = 8;
    else {
        const int* ra = rand_attn + ((b * H_ + h) * (NB_ - 2) + (qb - 1)) * R_;
        ra0 = ra[0]; ra1 = ra[1]; ra2 = ra[2];
        nkb = (qb == 1 || qb == NB_ - 2) ? 7 : 8;
    }

    // K staging geometry: thread owns K row rr, 16 cols at cc4*16
    const int rr  = t >> 2;
    const int cc4 = t & 3;
    const float* kbase = k + ((size_t)bh * M_ + rr) * 64 + cc4 * 16;
    const int kslot = (rr >> 4) * 2 + (cc4 >> 1);
    const int kr15  = rr & 15;
    const int kg0   = (cc4 & 1) * 2;

    // V staging geometry: thread owns 8 k-rows (oct8*8+j) x 2 d-cols (d0v, d0v+1)
    const int d0v  = (t & 31) * 2;
    const int oct8 = t >> 5;            // 0..7
    const float* vbase = v + (size_t)bh * M_ * 64 + (size_t)(oct8 * 8) * 64 + d0v;
    const int vslot = (d0v >> 4) * 2 + (oct8 >> 2);
    const int vidx  = (oct8 & 3) * 16 + (d0v & 15);

    // ---- Q B-fragments (held all kernel): lane holds Q[q0w + c][32dh + hh*8 + j]
    bf16x8 qf[2];
    {
        const float* qp = q + ((size_t)bh * M_ + (size_t)qb * 64 + w * 16 + c) * 64 + hh * 8;
        #pragma unroll
        for (int dh = 0; dh < 2; ++dh) {
            float4 a0 = *(const float4*)(qp + dh * 32);
            float4 a1 = *(const float4*)(qp + dh * 32 + 4);
            bf16x8 qv;
            qv[0] = bf16s(a0.x); qv[1] = bf16s(a0.y); qv[2] = bf16s(a0.z); qv[3] = bf16s(a0.w);
            qv[4] = bf16s(a1.x); qv[5] = bf16s(a1.y); qv[6] = bf16s(a1.z); qv[7] = bf16s(a1.w);
            qf[dh] = qv;
        }
    }

    const float fbv = from_blocked[(b * NB_ + qb) * 64 + (w * 16 + c)];

    float mrun = -INFINITY, lrun = 0.0f;   // mrun in log2 domain
    f32x4 O[4];
    #pragma unroll
    for (int nf = 0; nf < 4; ++nf) { O[nf][0] = 0.f; O[nf][1] = 0.f; O[nf][2] = 0.f; O[nf][3] = 0.f; }

    float4 kr0, kr1, kr2, kr3;
    float2 vr[8];

    // ---- prologue: tile 0 -> regs -> buf 0; then issue loads for tile 1
    {
        const int kb0 = tile_kb(e, ch, qb, ra0, ra1, ra2, 0);
        const float4* kp4 = (const float4*)(kbase + (size_t)kb0 * 4096);
        kr0 = kp4[0]; kr1 = kp4[1]; kr2 = kp4[2]; kr3 = kp4[3];
        const float* vp = vbase + (size_t)kb0 * 4096;
        #pragma unroll
        for (int j = 0; j < 8; ++j) vr[j] = *(const float2*)(vp + j * 64);

        float kfl[16];
        kfl[0]=kr0.x; kfl[1]=kr0.y; kfl[2]=kr0.z; kfl[3]=kr0.w;
        kfl[4]=kr1.x; kfl[5]=kr1.y; kfl[6]=kr1.z; kfl[7]=kr1.w;
        kfl[8]=kr2.x; kfl[9]=kr2.y; kfl[10]=kr2.z; kfl[11]=kr2.w;
        kfl[12]=kr3.x; kfl[13]=kr3.y; kfl[14]=kr3.z; kfl[15]=kr3.w;
        bf16x8 o0, o1;
        #pragma unroll
        for (int j = 0; j < 8; ++j) { o0[j] = bf16s(kfl[j]); o1[j] = bf16s(kfl[8 + j]); }
        kf[0][kslot][kg0 * 16 + kr15]       = __builtin_bit_cast(int4, o0);
        kf[0][kslot][(kg0 + 1) * 16 + kr15] = __builtin_bit_cast(int4, o1);

        bf16x8 va, vb2;
        #pragma unroll
        for (int j = 0; j < 8; ++j) { va[j] = bf16s(vr[j].x); vb2[j] = bf16s(vr[j].y); }
        vf[0][vslot][vidx]     = __builtin_bit_cast(int4, va);
        vf[0][vslot][vidx + 1] = __builtin_bit_cast(int4, vb2);

        if (1 < nkb) {   // issue loads for tile 1 (land across the barrier)
            const int kb1 = tile_kb(e, ch, qb, ra0, ra1, ra2, 1);
            const float4* kn4 = (const float4*)(kbase + (size_t)kb1 * 4096);
            kr0 = kn4[0]; kr1 = kn4[1]; kr2 = kn4[2]; kr3 = kn4[3];
            const float* vn = vbase + (size_t)kb1 * 4096;
            #pragma unroll
            for (int j = 0; j < 8; ++j) vr[j] = *(const float2*)(vn + j * 64);
        }
    }
    __syncthreads();

    for (int it = 0; it < nkb; ++it) {
        const int cur = it & 1;
        const int kb = tile_kb(e, ch, qb, ra0, ra1, ra2, it);
        int mode = 0, boff = 0;
        if (e < 0) {
            if (qb == 1 || qb == NB_ - 2) { mode = (it >= 4) ? 2 : 0; }
            else {
                if (it >= 1 && it < 4)      { mode = 1; boff = (it - 1) * 64; }
                else if (it >= 4 && it < 7) { mode = 2; }
            }
        }

        // ---- S^T = K * Q^T : lane holds S[q = c][k = 16f + 4hh + r]
        f32x4 sf[4];
        #pragma unroll
        for (int f = 0; f < 4; ++f) { sf[f][0]=0.f; sf[f][1]=0.f; sf[f][2]=0.f; sf[f][3]=0.f; }
        __builtin_amdgcn_s_setprio(1);
        #pragma unroll
        for (int f = 0; f < 4; ++f) {
            sf[f] = __builtin_amdgcn_mfma_f32_16x16x32_bf16(
                        __builtin_bit_cast(bf16x8, kf[cur][f * 2 + 0][l]), qf[0], sf[f], 0, 0, 0);
            sf[f] = __builtin_amdgcn_mfma_f32_16x16x32_bf16(
                        __builtin_bit_cast(bf16x8, kf[cur][f * 2 + 1][l]), qf[1], sf[f], 0, 0, 0);
        }
        __builtin_amdgcn_s_setprio(0);

        // ---- masks (vectorized float4 loads)
        float msk[4][4];
        if (mode == 0) {
            const float* mp = to_mask + b * M_ + kb * 64 + 4 * hh;
            #pragma unroll
            for (int f = 0; f < 4; ++f) {
                float4 mv = *(const float4*)(mp + 16 * f);
                msk[f][0] = mv.x; msk[f][1] = mv.y; msk[f][2] = mv.z; msk[f][3] = mv.w;
            }
        } else if (mode == 1) {
            const float* mp = band_mask + (((size_t)b * (NB_ - 4) + (qb - 2)) * 64 + (w * 16 + c)) * 192 + boff + 4 * hh;
            #pragma unroll
            for (int f = 0; f < 4; ++f) {
                float4 mv = *(const float4*)(mp + 16 * f);
                msk[f][0] = mv.x; msk[f][1] = mv.y; msk[f][2] = mv.z; msk[f][3] = mv.w;
            }
        } else {
            const float* mp = to_blocked + (b * NB_ + kb) * 64 + 4 * hh;
            #pragma unroll
            for (int f = 0; f < 4; ++f) {
                float4 mv = *(const float4*)(mp + 16 * f);
                msk[f][0] = fbv * mv.x; msk[f][1] = fbv * mv.y;
                msk[f][2] = fbv * mv.z; msk[f][3] = fbv * mv.w;
            }
        }

        // ---- scale + mask + online softmax, log2 domain (lane-local + 2 shfl_xor)
        float p[4][4];
        float tmax = -INFINITY;
        #pragma unroll
        for (int f = 0; f < 4; ++f) {
            #pragma unroll
            for (int r = 0; r < 4; ++r) {
                const float s = sf[f][r] * SCALE2 + (1.0f - msk[f][r]) * NEG2;
                p[f][r] = s;
                tmax = fmaxf(tmax, s);
            }
        }
        tmax = fmaxf(tmax, __shfl_xor(tmax, 16));
        tmax = fmaxf(tmax, __shfl_xor(tmax, 32));
        const float mnew = fmaxf(mrun, tmax);
        const float fs = exp2f(mrun - mnew);   // 0 on first tile
        float sum = 0.0f;
        #pragma unroll
        for (int f = 0; f < 4; ++f) {
            #pragma unroll
            for (int r = 0; r < 4; ++r) { p[f][r] = exp2f(p[f][r] - mnew); sum += p[f][r]; }
        }
        sum += __shfl_xor(sum, 16);
        sum += __shfl_xor(sum, 32);
        lrun = lrun * fs + sum;
        mrun = mnew;

        // ---- rescale O (rows are q = 4hh + r -> fetch fs from lane 4hh+r)
        const float fr0 = __shfl(fs, hh * 4 + 0);
        const float fr1 = __shfl(fs, hh * 4 + 1);
        const float fr2 = __shfl(fs, hh * 4 + 2);
        const float fr3 = __shfl(fs, hh * 4 + 3);
        #pragma unroll
        for (int nf = 0; nf < 4; ++nf) {
            O[nf][0] *= fr0; O[nf][1] *= fr1; O[nf][2] *= fr2; O[nf][3] *= fr3;
        }

        // ---- P -> bf16, redistribute to PV A-frag layout (in-wave shuffles)
        unsigned pks[4][2];
        #pragma unroll
        for (int f = 0; f < 4; ++f) {
            pks[f][0] = pack_bf16(p[f][0], p[f][1]);
            pks[f][1] = pack_bf16(p[f][2], p[f][3]);
        }
        #pragma unroll
        for (int kh = 0; kh < 2; ++kh) {
            unsigned ad[4];
            #pragma unroll
            for (int wq = 0; wq < 4; ++wq) {
                const int pos = wq >> 1, ww = wq & 1;
                const int src = c + 16 * ((2 * hh + pos) & 3);
                const unsigned x = (unsigned)__shfl((int)pks[2 * kh][ww], src);
                const unsigned y = (unsigned)__shfl((int)pks[2 * kh + 1][ww], src);
                ad[wq] = (hh & 2) ? y : x;
            }
            const uint4 adv = make_uint4(ad[0], ad[1], ad[2], ad[3]);
            const bf16x8 pa = __builtin_bit_cast(bf16x8, adv);
            __builtin_amdgcn_s_setprio(1);
            #pragma unroll
            for (int nf = 0; nf < 4; ++nf) {
                O[nf] = __builtin_amdgcn_mfma_f32_16x16x32_bf16(
                            pa, __builtin_bit_cast(bf16x8, vf[cur][nf * 2 + kh][l]), O[nf], 0, 0, 0);
            }
            __builtin_amdgcn_s_setprio(0);
        }

        // ---- write tile it+1 into the other buffer (regs loaded last iter),
        //      then issue loads for tile it+2 BEFORE the barrier.
        if (it + 1 < nkb) {
            const int nxt = cur ^ 1;
            float kfl[16];
            kfl[0]=kr0.x; kfl[1]=kr0.y; kfl[2]=kr0.z; kfl[3]=kr0.w;
            kfl[4]=kr1.x; kfl[5]=kr1.y; kfl[6]=kr1.z; kfl[7]=kr1.w;
            kfl[8]=kr2.x; kfl[9]=kr2.y; kfl[10]=kr2.z; kfl[11]=kr2.w;
            kfl[12]=kr3.x; kfl[13]=kr3.y; kfl[14]=kr3.z; kfl[15]=kr3.w;
            bf16x8 o0, o1;
            #pragma unroll
            for (int j = 0; j < 8; ++j) { o0[j] = bf16s(kfl[j]); o1[j] = bf16s(kfl[8 + j]); }
            kf[nxt][kslot][kg0 * 16 + kr15]       = __builtin_bit_cast(int4, o0);
            kf[nxt][kslot][(kg0 + 1) * 16 + kr15] = __builtin_bit_cast(int4, o1);

            bf16x8 va, vb2;
            #pragma unroll
            for (int j = 0; j < 8; ++j) { va[j] = bf16s(vr[j].x); vb2[j] = bf16s(vr[j].y); }
            vf[nxt][vslot][vidx]     = __builtin_bit_cast(int4, va);
            vf[nxt][vslot][vidx + 1] = __builtin_bit_cast(int4, vb2);

            if (it + 2 < nkb) {
                const int kbn = tile_kb(e, ch, qb, ra0, ra1, ra2, it + 2);
                const float4* kp4 = (const float4*)(kbase + (size_t)kbn * 4096);
                kr0 = kp4[0]; kr1 = kp4[1]; kr2 = kp4[2]; kr3 = kp4[3];
                const float* vp = vbase + (size_t)kbn * 4096;
                #pragma unroll
                for (int j = 0; j < 8; ++j) vr[j] = *(const float2*)(vp + j * 64);
            }
        }
        __syncthreads();
    }

    // ---- epilogue: O rows are q_local = w*16 + 4hh + r, cols d = nf*16 + c
    if (e < 0) {
        #pragma unroll
        for (int r = 0; r < 4; ++r) {
            const float lr  = __shfl(lrun, hh * 4 + r);
            const int   qg  = qb * 64 + w * 16 + hh * 4 + r;
            const float fmv = from_mask[b * M_ + qg];
            const float scl = fmv / lr;
            float* op = out + (((size_t)b * M_ + qg) * H_ + h) * 64 + c;
            #pragma unroll
            for (int nf = 0; nf < 4; ++nf) op[nf * 16] = O[nf][r] * scl;
        }
    } else {
        const int pe = (bh * 2 + e) * 8 + ch;
        #pragma unroll
        for (int r = 0; r < 4; ++r) {
            const int qlocal = w * 16 + hh * 4 + r;
            float* pa = ws + PACC_OFF + ((size_t)pe * 64 + qlocal) * 64 + c;
            #pragma unroll
            for (int nf = 0; nf < 4; ++nf) pa[nf * 16] = O[nf][r];
        }
        if (hh == 0) {
            ws[PM_OFF + pe * 64 + w * 16 + c] = mrun;   // log2 domain
            ws[PL_OFF + pe * 64 + w * 16 + c] = lrun;
        }
    }
}

// Combine the 8 partials for each edge q-block row (m in log2 domain).
__global__ __launch_bounds__(256)
void bigbird_combine(const float* __restrict__ ws, const float* __restrict__ from_mask,
                     float* __restrict__ out)
{
    const int g  = blockIdx.x;          // bh*2 + e
    const int e  = g & 1;
    const int bh = g >> 1;
    const int h  = bh % H_;
    const int b  = bh / H_;
    const int qb = e ? NB_ - 1 : 0;

    const int t  = threadIdx.x;
    const int r  = t >> 2;
    const int dq = (t & 3) * 16;

    float mc[8], lc[8];
    float m = -INFINITY;
    #pragma unroll
    for (int c = 0; c < 8; ++c) {
        mc[c] = ws[PM_OFF + (g * 8 + c) * 64 + r];
        lc[c] = ws[PL_OFF + (g * 8 + c) * 64 + r];
        m = fmaxf(m, mc[c]);
    }
    float l = 0.0f;
    float acc[16];
    #pragma unroll
    for (int j = 0; j < 16; ++j) acc[j] = 0.0f;
    #pragma unroll
    for (int c = 0; c < 8; ++c) {
        const float sc = exp2f(mc[c] - m);
        l += lc[c] * sc;
        const float4* pa = (const float4*)(ws + PACC_OFF + ((size_t)(g * 8 + c) * 64 + r) * 64 + dq);
        #pragma unroll
        for (int j4 = 0; j4 < 4; ++j4) {
            float4 av = pa[j4];
            acc[j4 * 4 + 0] += sc * av.x;
            acc[j4 * 4 + 1] += sc * av.y;
            acc[j4 * 4 + 2] += sc * av.z;
            acc[j4 * 4 + 3] += sc * av.w;
        }
    }
    const float fm = from_mask[b * M_ + qb * 64 + r];
    const float s  = fm / l;
    float* op = out + (((size_t)b * M_ + qb * 64 + r) * H_ + h) * 64 + dq;
    #pragma unroll
    for (int j4 = 0; j4 < 4; ++j4) {
        float4 o;
        o.x = acc[j4 * 4 + 0] * s; o.y = acc[j4 * 4 + 1] * s;
        o.z = acc[j4 * 4 + 2] * s; o.w = acc[j4 * 4 + 3] * s;
        *(float4*)(op + j4 * 4) = o;
    }
}

extern "C" void kernel_launch(void* const* d_in, const int* in_sizes, int n_in,
                              void* d_out, int out_size, void* d_ws, size_t ws_size,
                              hipStream_t stream) {
    const float* q  = (const float*)d_in[0];
    const float* k  = (const float*)d_in[1];
    const float* v  = (const float*)d_in[2];
    const float* bm = (const float*)d_in[3];
    const float* fm = (const float*)d_in[4];
    const float* tm = (const float*)d_in[5];
    const float* fb = (const float*)d_in[6];
    const float* tb = (const float*)d_in[7];
    const int*   ra = (const int*)d_in[8];
    float* o  = (float*)d_out;
    float* ws = (float*)d_ws;

    hipLaunchKernelGGL(bigbird_mfma, dim3(NWG), dim3(256), 0, stream,
                       q, k, v, bm, fm, tm, fb, tb, ra, o, ws);
    hipLaunchKernelGGL(bigbird_combine, dim3(B_ * H_ * 2), dim3(256), 0, stream,
                       ws, fm, o);
}